// Round 9
// baseline (61.539 us; speedup 1.0000x reference)
//
#include <hip/hip_runtime.h>
#include <hip/hip_bf16.h>
#include <math.h>

// out[b,i,j,o] = lrelu( sum_k pe[d_k]@W_k[:,o] + b[o] )
// (1) Y precompute (fp32 math, bf16 store) into COLUMN-SPLIT layout
//     Yc[c][k][r][128], c = col>>7. Each slice = 1.05 MB.
// (2) gather: grid ordered so all c=0 blocks run before c=1 -> per-phase
//     L2 working set is one 1.05 MB slice (vs 2.1 MB), resisting eviction
//     by the 134 MB NT-store stream. 2 j's per wave (measured optimum:
//     1j=69us, 2j=52us, 4j=56us, 16j=60us).

typedef float f32x4 __attribute__((ext_vector_type(4)));

__device__ __forceinline__ float lrelu(float x) { return fmaxf(x, 0.01f * x); }
__device__ __forceinline__ float bflo(unsigned int v) {
    union { unsigned int i; float f; } c; c.i = v << 16; return c.f;
}
__device__ __forceinline__ float bfhi(unsigned int v) {
    union { unsigned int i; float f; } c; c.i = v & 0xffff0000u; return c.f;
}

// ---------------- Kernel 1: Y precompute (R4 math, split-layout store) --------
__global__ __launch_bounds__(256) void precompute_Ys(
        const float* __restrict__ pe, const float* __restrict__ W,
        const float* __restrict__ bias, __hip_bfloat16* __restrict__ Yc, int NPE) {
    const int H = 256;
    const int ntile = (NPE + 7) >> 3;
    const int k  = blockIdx.x / ntile;
    const int r0 = (blockIdx.x % ntile) << 3;
    const int o  = threadIdx.x;
    const float* __restrict__ Wk = W + (size_t)k * H * H;

    int rows[8];
#pragma unroll
    for (int r = 0; r < 8; ++r) rows[r] = min(r0 + r, NPE - 1);
    float acc[8];
#pragma unroll
    for (int r = 0; r < 8; ++r) acc[r] = 0.f;

#pragma unroll 2
    for (int h = 0; h < 256; h += 4) {
        const float w0 = Wk[(h + 0) * H + o];
        const float w1 = Wk[(h + 1) * H + o];
        const float w2 = Wk[(h + 2) * H + o];
        const float w3 = Wk[(h + 3) * H + o];
#pragma unroll
        for (int r = 0; r < 8; ++r) {
            const f32x4 p = *reinterpret_cast<const f32x4*>(&pe[rows[r] * H + h]);
            acc[r] += p.x * w0 + p.y * w1 + p.z * w2 + p.w * w3;
        }
    }
    const float bv = (k == 0) ? bias[o] : 0.f;
    const int c   = o >> 7;          // column slice
    const int col = o & 127;
#pragma unroll
    for (int r = 0; r < 8; ++r) {
        const int rr = r0 + r;
        if (rr < NPE)
            Yc[((size_t)((c * 4 + k) * NPE + rr) << 7) + col] =
                __float2bfloat16(acc[r] + bv);
    }
}

// ---------------- Kernel 2: gather, column-split two-phase --------------------
// grid.x = 2 * B*S*(S/8); c = slowest grid dim (phase). Block: (c, b, i, 8 j's).
// Wave w: j-pair (2w, 2w+1); lane half (ln>>5) selects j, lc=ln&31 selects
// 4 cols. Per wave: 2 pos loads + 4 row loads (8B/lane) + 1 NT f32x4 store.
__global__ __launch_bounds__(256) void gather_split(
        const int* __restrict__ pos_s, const int* __restrict__ pos_e,
        const __hip_bfloat16* __restrict__ Yc, float* __restrict__ out,
        int S, int ML, int NPE) {
    const int S8   = S >> 3;
    const int half = gridDim.x >> 1;

    const int c  = (blockIdx.x >= half) ? 1 : 0;
    const int rb = blockIdx.x - c * half;

    const int jt = rb % S8;
    const int i  = (rb / S8) % S;
    const int bb = rb / (S8 * S);

    const int t  = threadIdx.x;
    const int w  = t >> 6;
    const int ln = t & 63;
    const int hf = ln >> 5;          // 0 -> j0, 1 -> j1
    const int lc = ln & 31;          // uint2 lane within 128-col slice

    const int jh = (jt << 3) + (w << 1) + hf;

    const int si = pos_s[bb * S + i];
    const int ei = pos_e[bb * S + i];
    const int sjh = pos_s[bb * S + jh];
    const int ejh = pos_e[bb * S + jh];

    const int cOff = c * 4 * NPE;
    const int r0 = cOff + 0 * NPE + si - sjh + ML;
    const int r1 = cOff + 1 * NPE + si - ejh + ML;
    const int r2 = cOff + 2 * NPE + ei - sjh + ML;
    const int r3 = cOff + 3 * NPE + ei - ejh + ML;

    const uint2* __restrict__ Yv = reinterpret_cast<const uint2*>(Yc);
    const uint2 u0 = Yv[((size_t)r0 << 5) + lc];
    const uint2 u1 = Yv[((size_t)r1 << 5) + lc];
    const uint2 u2 = Yv[((size_t)r2 << 5) + lc];
    const uint2 u3 = Yv[((size_t)r3 << 5) + lc];

    f32x4 v;
    v.x = lrelu(bflo(u0.x) + bflo(u1.x) + bflo(u2.x) + bflo(u3.x));
    v.y = lrelu(bfhi(u0.x) + bfhi(u1.x) + bfhi(u2.x) + bfhi(u3.x));
    v.z = lrelu(bflo(u0.y) + bflo(u1.y) + bflo(u2.y) + bflo(u3.y));
    v.w = lrelu(bfhi(u0.y) + bfhi(u1.y) + bfhi(u2.y) + bfhi(u3.y));

    f32x4* __restrict__ ov = reinterpret_cast<f32x4*>(out);
    __builtin_nontemporal_store(
        v, &ov[((((size_t)bb * S + i) * S + jh) << 6) + (c << 5) + lc]);
}

// ---------------- Fallback: direct compute ------------------------------------
__global__ void direct_kernel(const int* __restrict__ pos_s,
                              const int* __restrict__ pos_e,
                              const float* __restrict__ pe,
                              const float* __restrict__ W,
                              const float* __restrict__ bias,
                              float* __restrict__ out,
                              int B, int S, int H, int ML) {
    const int blk = blockIdx.x;
    const int j   = blk % S;
    const int i   = (blk / S) % S;
    const int bb  = blk / (S * S);
    const int o   = threadIdx.x;
    const int si = pos_s[bb * S + i];
    const int ei = pos_e[bb * S + i];
    const int sj = pos_s[bb * S + j];
    const int ej = pos_e[bb * S + j];
    const int rss = si - sj + ML, rse = si - ej + ML;
    const int res = ei - sj + ML, ree = ei - ej + ML;
    float acc = bias[o];
    for (int h = 0; h < H; ++h) {
        acc += pe[rss * H + h] * W[(0 * H + h) * H + o];
        acc += pe[rse * H + h] * W[(1 * H + h) * H + o];
        acc += pe[res * H + h] * W[(2 * H + h) * H + o];
        acc += pe[ree * H + h] * W[(3 * H + h) * H + o];
    }
    out[(((size_t)bb * S + i) * S + j) * H + o] = lrelu(acc);
}

extern "C" void kernel_launch(void* const* d_in, const int* in_sizes, int n_in,
                              void* d_out, int out_size, void* d_ws, size_t ws_size,
                              hipStream_t stream) {
    const int*   pos_s = (const int*)d_in[0];
    const int*   pos_e = (const int*)d_in[1];
    const float* pe    = (const float*)d_in[2];
    const float* W     = (const float*)d_in[3];
    const float* bias  = (const float*)d_in[4];
    float*       out   = (float*)d_out;

    const int H   = in_sizes[4];                 // 256
    const int NPE = in_sizes[2] / H;             // 1025
    const int ML  = (NPE - 1) / 2;               // 512
    const int BS  = in_sizes[0];
    const int S   = (int)((long long)out_size / ((long long)BS * H)); // 256
    const int B   = BS / S;

    const size_t ybytes = (size_t)8 * NPE * 128 * sizeof(__hip_bfloat16); // 2.1 MB

    if (H == 256 && (S & 7) == 0 && ws_size >= ybytes) {
        __hip_bfloat16* Yc = (__hip_bfloat16*)d_ws;
        const int ntile = (NPE + 7) >> 3;
        precompute_Ys<<<4 * ntile, 256, 0, stream>>>(pe, W, bias, Yc, NPE);
        const int nblk = 2 * B * S * (S >> 3);
        gather_split<<<nblk, 256, 0, stream>>>(pos_s, pos_e, Yc, out, S, ML, NPE);
    } else {
        direct_kernel<<<B * S * S, H, 0, stream>>>(pos_s, pos_e, pe, W, bias, out,
                                                   B, S, H, ML);
    }
}